// Round 8
// baseline (4879.384 us; speedup 1.0000x reference)
//
#include <hip/hip_runtime.h>
#include <stdint.h>

// ---------- types / helpers ----------
typedef __attribute__((ext_vector_type(8))) short short8;   // 8 bf16 in 4 VGPRs
typedef __attribute__((ext_vector_type(4))) float f32x4;

__device__ __forceinline__ unsigned short f32_to_bf16(float f) {
    unsigned int u = __float_as_uint(f);
    unsigned int r = (u + 0x7FFF + ((u >> 16) & 1)) >> 16;   // RNE
    return (unsigned short)r;
}
__device__ __forceinline__ float bf16_to_f32(unsigned short s) {
    return __uint_as_float(((unsigned int)s) << 16);
}

// ---------- prep kernels ----------
__global__ void cvt_bf16_kernel(const float* __restrict__ in,
                                unsigned short* __restrict__ out, int n) {
    int i = (blockIdx.x * blockDim.x + threadIdx.x) * 4;
    if (i >= n) return;
    float4 v = *(const float4*)(in + i);
    ushort4 o;
    o.x = f32_to_bf16(v.x);
    o.y = f32_to_bf16(v.y);
    o.z = f32_to_bf16(v.z);
    o.w = f32_to_bf16(v.w);
    *(ushort4*)(out + i) = o;
}

__global__ void bias_add_kernel(const float* __restrict__ bi,
                                const float* __restrict__ bh,
                                float* __restrict__ bias) {
    int i = blockIdx.x * blockDim.x + threadIdx.x;  // 4096
    bias[i] = bi[i] + bh[i];
}

__global__ void zero_kernel(unsigned int* __restrict__ p, int n) {
    int i = blockIdx.x * blockDim.x + threadIdx.x;
    if (i < n) p[i] = 0u;
}

// ---------- phase 1: xg[r][g] = bf16( x[r][:]·W_ih[g][:] + bias[g] ), r=b*512+t ----------
#define LDP 40  // padded LDS row pitch (shorts)

__global__ __launch_bounds__(256) void gemm_xproj(
    const unsigned short* __restrict__ A,   // x bf16 [16384][1024]
    const unsigned short* __restrict__ B,   // W_ih bf16 [4096][1024]
    const float* __restrict__ bias,         // [4096]
    unsigned short* __restrict__ C) {       // xg bf16 [16384][4096]
    __shared__ unsigned short As[64][LDP];
    __shared__ unsigned short Bs[64][LDP];
    const int tid  = threadIdx.x;
    const int lane = tid & 63;
    const int wave = tid >> 6;
    const int m0 = blockIdx.y * 64;
    const int n0 = blockIdx.x * 64;
    const int wm = (wave & 1) * 32;
    const int wn = (wave >> 1) * 32;

    f32x4 acc[2][2] = {};

    const int sr = tid >> 2;
    const int sk = (tid & 3) * 8;
    const int fr = lane & 15;
    const int fk = (lane >> 4) * 8;

    for (int k0 = 0; k0 < 1024; k0 += 32) {
        uint4 av = *(const uint4*)&A[(m0 + sr) * 1024 + k0 + sk];
        uint4 bv = *(const uint4*)&B[(n0 + sr) * 1024 + k0 + sk];
        __syncthreads();
        *(uint4*)&As[sr][sk] = av;
        *(uint4*)&Bs[sr][sk] = bv;
        __syncthreads();
        short8 a0 = *(const short8*)&As[wm + fr][fk];
        short8 a1 = *(const short8*)&As[wm + 16 + fr][fk];
        short8 b0 = *(const short8*)&Bs[wn + fr][fk];
        short8 b1 = *(const short8*)&Bs[wn + 16 + fr][fk];
        acc[0][0] = __builtin_amdgcn_mfma_f32_16x16x32_bf16(a0, b0, acc[0][0], 0, 0, 0);
        acc[0][1] = __builtin_amdgcn_mfma_f32_16x16x32_bf16(a0, b1, acc[0][1], 0, 0, 0);
        acc[1][0] = __builtin_amdgcn_mfma_f32_16x16x32_bf16(a1, b0, acc[1][0], 0, 0, 0);
        acc[1][1] = __builtin_amdgcn_mfma_f32_16x16x32_bf16(a1, b1, acc[1][1], 0, 0, 0);
    }

    const int col = lane & 15;
    const int rq  = (lane >> 4) * 4;
    for (int mt = 0; mt < 2; mt++) {
        for (int nt = 0; nt < 2; nt++) {
            int gcol = n0 + wn + nt * 16 + col;
            float bv = bias[gcol];
            for (int r = 0; r < 4; r++) {
                int grow = m0 + wm + mt * 16 + rq + r;
                C[(size_t)grow * 4096 + gcol] = f32_to_bf16(acc[mt][nt][r] + bv);
            }
        }
    }
}

// ---------- phase 2: persistent recurrence ----------
// 128 blocks x 256 threads (4 waves, 1 block/CU). Block bid owns 8 hidden units
// j0=8*bid..+7. A-fragments (W_hh slice, bf16) live in per-lane REGISTERS
// (short8 areg[32], loaded once) — no LDS A reads in the loop.
// LDS: staged h (32 batch x 1024 bf16, row stride 1032) 64.5 KB + hpack 512 B.
// Waves: (mt = j-half, nt = batch-half), each full K=1024 -> 32 MFMAs, no
// K-split. Lane (fr=batch-col, quad) acc[r] = gate r of (j=j0+mt*4+quad,
// b=nt*16+fr): epilogue fully in-lane, c-state in VGPRs.
// h staging: each thread owns a 256 B segment = 16 dwordx4 sc0/sc1 loads
// (round-7 bug: only 4 were loaded -> 3/4 of Hs poisoned).
// Publish: pack to LDS, wave 0 stores 32 x 2 dwordx2 sc1 + drain + flag;
// wave 1 polls 128 flags (dwordx2+ballot). Raw sc0/sc1 only — no compiler
// atomics (round-3 buffer_inv storm).
#define LSTR 1032

__global__ __launch_bounds__(256, 1) void lstm_persist(
    const float* __restrict__ Whh,          // [4096][1024] fp32
    const unsigned short* __restrict__ xg,  // bf16 [16384][4096], bias folded
    const float* __restrict__ c0,           // [32][1024] fp32
    unsigned short* __restrict__ hA,        // bf16 [32][1024], h(0) at entry
    unsigned short* __restrict__ hB,        // bf16 [32][1024]
    unsigned int* __restrict__ flags,       // [512][128]
    float* __restrict__ out) {              // [32][1024] fp32
    __shared__ unsigned short Hs[32 * LSTR];             // 64.5 KB
    __shared__ __align__(16) unsigned short hpack[256];  // [b][j_local 8]

    const int tid  = threadIdx.x;
    const int bid  = blockIdx.x;
    const int j0   = bid * 8;
    const int lane = tid & 63;
    const int wave = tid >> 6;
    const int mt   = wave >> 1;
    const int nt   = wave & 1;
    const int fr   = lane & 15;
    const int quad = lane >> 4;

    // ---- A-fragments -> registers (once) ----
    // A-operand layout: lane (fr=m, quad) holds A[m=fr][k=quad*8+j] per kc.
    // A row m = W_hh_bf16[gate q=m&3][j = j0 + mt*4 + (m>>2)]  (m = jin*4+q)
    short8 areg[32];
    {
        const int q = fr & 3, jin = fr >> 2;
        const float* wr = Whh + (size_t)(q * 1024 + j0 + mt * 4 + jin) * 1024 + quad * 8;
#pragma unroll
        for (int kc = 0; kc < 32; ++kc) {
            float4 va = *(const float4*)(wr + kc * 32);
            float4 vb = *(const float4*)(wr + kc * 32 + 4);
            short8 v;
            v[0] = f32_to_bf16(va.x); v[1] = f32_to_bf16(va.y);
            v[2] = f32_to_bf16(va.z); v[3] = f32_to_bf16(va.w);
            v[4] = f32_to_bf16(vb.x); v[5] = f32_to_bf16(vb.y);
            v[6] = f32_to_bf16(vb.z); v[7] = f32_to_bf16(vb.w);
            areg[kc] = v;
        }
    }

    // this lane's (j, b) for epilogue (C layout: col=n=batch, quad*4+r=m)
    const int b = nt * 16 + fr;
    const int j = j0 + mt * 4 + quad;
    float cst = c0[b * 1024 + j];

    // xz prefetch for t=0 (gate q at xg row b*512+t, col q*1024+j)
    const unsigned short* xzp = xg + (size_t)(b * 512) * 4096 + j;
    unsigned short xzr0 = xzp[0], xzr1 = xzp[1024], xzr2 = xzp[2048], xzr3 = xzp[3072];

    // h staging: thread covers row=tid&31 (batch), 128-short seg = tid>>5
    const int srow = tid & 31, sseg = tid >> 5;
    const int sgo  = srow * 1024 + sseg * 128;   // global offset (shorts)
    const int slo  = srow * LSTR + sseg * 128;   // LDS offset (shorts)

    const unsigned short* bp = &Hs[(nt * 16 + fr) * LSTR + quad * 8];

    for (int t = 0; t < 512; ++t) {
        const unsigned short* hR = (t & 1) ? hB : hA;
        unsigned short*       hW = (t & 1) ? hA : hB;

        // ---- stage h(t) -> LDS: full 256 B segment per thread ----
        {
            const unsigned short* s = hR + sgo;
            uint4 v0, v1, v2, v3, v4, v5, v6, v7, v8, v9, v10, v11, v12, v13, v14, v15;
#define LDH(i, off) asm volatile("global_load_dwordx4 %0, %1, off offset:" #off " sc0 sc1" \
                                 : "=v"(v##i) : "v"(s) : "memory")
            LDH(0, 0);    LDH(1, 16);   LDH(2, 32);   LDH(3, 48);
            LDH(4, 64);   LDH(5, 80);   LDH(6, 96);   LDH(7, 112);
            LDH(8, 128);  LDH(9, 144);  LDH(10, 160); LDH(11, 176);
            LDH(12, 192); LDH(13, 208); LDH(14, 224); LDH(15, 240);
#undef LDH
            asm volatile("s_waitcnt vmcnt(0)" ::: "memory");
            *(uint4*)&Hs[slo]       = v0;  *(uint4*)&Hs[slo + 8]   = v1;
            *(uint4*)&Hs[slo + 16]  = v2;  *(uint4*)&Hs[slo + 24]  = v3;
            *(uint4*)&Hs[slo + 32]  = v4;  *(uint4*)&Hs[slo + 40]  = v5;
            *(uint4*)&Hs[slo + 48]  = v6;  *(uint4*)&Hs[slo + 56]  = v7;
            *(uint4*)&Hs[slo + 64]  = v8;  *(uint4*)&Hs[slo + 72]  = v9;
            *(uint4*)&Hs[slo + 80]  = v10; *(uint4*)&Hs[slo + 88]  = v11;
            *(uint4*)&Hs[slo + 96]  = v12; *(uint4*)&Hs[slo + 104] = v13;
            *(uint4*)&Hs[slo + 112] = v14; *(uint4*)&Hs[slo + 120] = v15;
        }
        __syncthreads();

        // ---- full-K MFMA: A from registers, B (h) from LDS ----
        f32x4 acc = {0.f, 0.f, 0.f, 0.f};
#pragma unroll
        for (int kc = 0; kc < 32; ++kc) {
            short8 h = *(const short8*)(bp + kc * 32);
            acc = __builtin_amdgcn_mfma_f32_16x16x32_bf16(areg[kc], h, acc, 0, 0, 0);
        }

        // ---- in-lane epilogue: acc[r] = gate r of (j, b) ----
        float z0 = acc[0] + bf16_to_f32(xzr0);
        float z1 = acc[1] + bf16_to_f32(xzr1);
        float z2 = acc[2] + bf16_to_f32(xzr2);
        float z3 = acc[3] + bf16_to_f32(xzr3);
        float ig = 1.f / (1.f + __expf(-z0));
        float fg = 1.f / (1.f + __expf(-z1));
        float gg = tanhf(z2);
        float og = 1.f / (1.f + __expf(-z3));
        cst = fg * cst + ig * gg;
        float hn = og * tanhf(cst);

        if (t == 511) {
            out[b * 1024 + j] = hn;   // final fp32 output
            break;                    // uniform
        }

        hpack[b * 8 + mt * 4 + quad] = f32_to_bf16(hn);
        // xz prefetch for t+1 (completes during publish/poll)
        {
            const unsigned short* p = xg + (size_t)(b * 512 + t + 1) * 4096 + j;
            xzr0 = p[0]; xzr1 = p[1024]; xzr2 = p[2048]; xzr3 = p[3072];
        }
        __syncthreads();   // hpack complete; Hs reads done -> safe to restage

        if (wave == 0) {
            // packed publish: 32 lanes x 16 B (two dwordx2)
            if (lane < 32) {
                uint2 hv0 = *(const uint2*)&hpack[lane * 8];
                uint2 hv1 = *(const uint2*)&hpack[lane * 8 + 4];
                unsigned short* dp = hW + lane * 1024 + j0;
                asm volatile("global_store_dwordx2 %0, %1, off sc1"
                             :: "v"(dp), "v"(hv0) : "memory");
                asm volatile("global_store_dwordx2 %0, %1, off offset:8 sc1"
                             :: "v"(dp), "v"(hv1) : "memory");
            }
            asm volatile("s_waitcnt vmcnt(0)" ::: "memory");
            if (lane == 0) {
                unsigned int one = 1u;
                asm volatile("global_store_dword %0, %1, off sc0 sc1"
                             :: "v"(flags + (size_t)t * 128 + bid), "v"(one) : "memory");
            }
        }
        if (wave == 1) {
            // poll: lane covers flags[2*lane], flags[2*lane+1]
            const unsigned int* fp = flags + (size_t)t * 128 + lane * 2;
            while (true) {
                uint2 v;
                asm volatile("global_load_dwordx2 %0, %1, off sc0 sc1\n\ts_waitcnt vmcnt(0)"
                             : "=v"(v) : "v"(fp) : "memory");
                if (__ballot((v.x & v.y) != 0u) == ~0ull) break;
            }
        }
        __syncthreads();
    }
}

// ---------- launch ----------
extern "C" void kernel_launch(void* const* d_in, const int* in_sizes, int n_in,
                              void* d_out, int out_size, void* d_ws, size_t ws_size,
                              hipStream_t stream) {
    const float* x    = (const float*)d_in[0];  // [32][512][1024]
    const float* h0   = (const float*)d_in[1];  // [32][1024]
    const float* c0   = (const float*)d_in[2];  // [32][1024]
    const float* Wih  = (const float*)d_in[3];  // [4096][1024]
    const float* Whh  = (const float*)d_in[4];  // [4096][1024]
    const float* b_ih = (const float*)d_in[5];  // [4096]
    const float* b_hh = (const float*)d_in[6];  // [4096]
    float* out = (float*)d_out;
    char* ws = (char*)d_ws;

    // workspace layout (within round-2-proven 176,439,296 B):
    //   xg    @ 0          134217728 B (bf16, live through persistent phase)
    //   xA    @ 134217728   33554432 B (bf16 x; DEAD after gemm -> flags overlay)
    //   wB    @ 167772160    8388608 B (bf16 W_ih)
    //   bias  @ 176160768      16384 B
    //   hA    @ 176177152      65536 B (bf16 [32][1024])
    //   hB    @ 176242688      65536 B
    unsigned short* xg   = (unsigned short*)(ws);
    unsigned short* xA   = (unsigned short*)(ws + 134217728);
    unsigned short* wB   = (unsigned short*)(ws + 167772160);
    float*          bias = (float*)(ws + 176160768);
    unsigned short* hA   = (unsigned short*)(ws + 176177152);
    unsigned short* hB   = (unsigned short*)(ws + 176242688);
    unsigned int*   flags = (unsigned int*)(ws + 134217728);  // overlays xA after gemm

    cvt_bf16_kernel<<<16384, 256, 0, stream>>>(x, xA, 16777216);
    cvt_bf16_kernel<<<4096, 256, 0, stream>>>(Wih, wB, 4194304);
    bias_add_kernel<<<16, 256, 0, stream>>>(b_ih, b_hh, bias);

    dim3 g1(64, 256);
    gemm_xproj<<<g1, 256, 0, stream>>>(xA, wB, bias, xg);

    // xA dead from here; reuse as flag storage (512 steps x 128 blocks)
    zero_kernel<<<256, 256, 0, stream>>>(flags, 512 * 128);
    // h(0): plain bf16 [b][j]
    cvt_bf16_kernel<<<32, 256, 0, stream>>>(h0, hA, 32768);

    lstm_persist<<<128, 256, 0, stream>>>(Whh, xg, c0, hA, hB, flags, out);
}